// Round 7
// baseline (904.416 us; speedup 1.0000x reference)
//
#include <hip/hip_runtime.h>
#include <hip/hip_bf16.h>
#include <hip/hip_fp16.h>

#define DIM 1024
#define NGROUPS 32
#define GSIZE 32
#define TT 1024
#define BB 16
#define MROWS (TT*BB)          // 16384 rows for all batched GEMMs
#define BD (BB*DIM)            // 16384 elems per timestep slab
#define G 16                   // scan group size (steps per reg buffer)
#define NG (TT/G)              // 64 groups (even)

typedef __attribute__((ext_vector_type(8))) short short8;
typedef __attribute__((ext_vector_type(4))) float f32x4;

// ---------- helpers ----------
__device__ __forceinline__ ushort f2b(float v) {
  __hip_bfloat16 b = __float2bfloat16(v);
  return *reinterpret_cast<ushort*>(&b);
}
__device__ __forceinline__ float b2f(ushort u) {
  __hip_bfloat16 b; *reinterpret_cast<ushort*>(&b) = u;
  return __bfloat162float(b);
}
__device__ __forceinline__ ushort f2h(float v) {
  __half h = __float2half(v);
  return *reinterpret_cast<ushort*>(&h);
}
__device__ __forceinline__ float softplusf(float z) {
  return (z > 20.f) ? z : log1pf(expf(z));
}
__device__ __forceinline__ float sigmoidf_(float z) { return 1.f/(1.f+expf(-z)); }

#define AS1(p) ((__attribute__((address_space(1))) void*)(void*)(p))
#define AS3(p) ((__attribute__((address_space(3))) void*)(void*)(p))

// ---------- split x into bf16 hi/lo ----------
__global__ __launch_bounds__(256) void split_x_kernel(
    const float4* __restrict__ x, ushort4* __restrict__ xh, ushort4* __restrict__ xl, int n4) {
  int i = blockIdx.x*256 + threadIdx.x;
  int stride = gridDim.x*256;
  for (; i < n4; i += stride) {
    float4 v = x[i];
    ushort4 h, l;
    h.x = f2b(v.x); l.x = f2b(v.x - b2f(h.x));
    h.y = f2b(v.y); l.y = f2b(v.y - b2f(h.y));
    h.z = f2b(v.z); l.z = f2b(v.z - b2f(h.z));
    h.w = f2b(v.w); l.w = f2b(v.w - b2f(h.w));
    xh[i] = h; xl[i] = l;
  }
}

// ---------- split/convert weights ----------
__global__ __launch_bounds__(256) void split_w_kernel(
    const float4* __restrict__ wx, const float4* __restrict__ wa,
    const float4* __restrict__ wd, const float4* __restrict__ wo,
    ushort4* __restrict__ wxh, ushort4* __restrict__ wxl,
    ushort4* __restrict__ wah, ushort4* __restrict__ wdh,
    ushort4* __restrict__ woh, int n4) {
  int i = blockIdx.x*256 + threadIdx.x;
  if (i >= n4) return;
  float4 v = wx[i];
  ushort4 h, l;
  h.x = f2b(v.x); l.x = f2b(v.x - b2f(h.x));
  h.y = f2b(v.y); l.y = f2b(v.y - b2f(h.y));
  h.z = f2b(v.z); l.z = f2b(v.z - b2f(h.z));
  h.w = f2b(v.w); l.w = f2b(v.w - b2f(h.w));
  wxh[i] = h; wxl[i] = l;
  float4 a = wa[i];
  ushort4 ha; ha.x=f2b(a.x); ha.y=f2b(a.y); ha.z=f2b(a.z); ha.w=f2b(a.w);
  wah[i] = ha;
  float4 d = wd[i];
  ushort4 hd; hd.x=f2b(d.x); hd.y=f2b(d.y); hd.z=f2b(d.z); hd.w=f2b(d.w);
  wdh[i] = hd;
  float4 o = wo[i];
  ushort4 ho; ho.x=f2b(o.x); ho.y=f2b(o.y); ho.z=f2b(o.z); ho.w=f2b(o.w);
  woh[i] = ho;
}

// LDS chunk swizzle (T2-adapted, rule 21: linear LDS dest for global_load_lds,
// inverse-swizzled SOURCE, swizzled READ).  s(row) = (row>>1)&3;
// LDS(row,c) holds global chunk c^s(row); reader of global chunk w reads
// LDS(row, w^s(row)).  Bank-quad = 4*(row&1) + chunk -> 8 distinct quads per
// 16-lane group -> 2-way (free) instead of 8-way.

// ---------- vx GEMM: vx = X @ Wx^T + b  (split-bf16 3-term, ~fp32 accurate) ----------
// 128x128 tile, 4 waves (2x2), per-wave 64x64 (frags 4x4). Round-5-proven shape.
__global__ __launch_bounds__(256) void gemm_vx_kernel(
    const ushort* __restrict__ Xh, const ushort* __restrict__ Xl,
    const ushort* __restrict__ Wxh, const ushort* __restrict__ Wxl,
    const float* __restrict__ b_v, float* __restrict__ vxout)
{
  __shared__ ushort As [128*32];
  __shared__ ushort AsL[128*32];
  __shared__ ushort Bs [128*32];
  __shared__ ushort BsL[128*32];

  const int tid  = threadIdx.x;
  const int lane = tid & 63;
  const int wid  = tid >> 6;
  const int wr   = wid >> 1, wc = wid & 1;

  // XCD swizzle: grid (8,128) -> 1024 blocks; bijective; xcd owns 16
  // contiguous row-panels x all 8 col-panels (A-panel L2 locality).
  const int did = blockIdx.y * 8 + blockIdx.x;
  const int xcd = did & 7;
  const int j   = did >> 3;
  const int m0  = (xcd * 16 + (j >> 3)) * 128;
  const int n0  = (j & 7) * 128;

  f32x4 acc[4][4];
  #pragma unroll
  for (int i=0;i<4;++i)
    #pragma unroll
    for (int jj=0;jj<4;++jj) acc[i][jj] = f32x4{0.f,0.f,0.f,0.f};

  const int fr = lane & 15;
  const int rc = (((lane >> 4) ^ ((fr >> 1) & 3))) * 8;   // swizzled read offset

  for (int ks = 0; ks < DIM/32; ++ks) {
    const int k0 = ks*32;
    #pragma unroll
    for (int jl = 0; jl < 2; ++jl) {
      int idx = jl*256 + tid;
      int row = idx >> 2;
      int cs  = ((idx & 3) ^ ((row >> 1) & 3)) * 8;       // pre-swizzled source
      size_t goffA = (size_t)(m0+row)*DIM + k0 + cs;
      size_t goffB = (size_t)(n0+row)*DIM + k0 + cs;
      __builtin_amdgcn_global_load_lds(AS1(Xh+goffA),  AS3(As +idx*8), 16, 0, 0);
      __builtin_amdgcn_global_load_lds(AS1(Xl+goffA),  AS3(AsL+idx*8), 16, 0, 0);
      __builtin_amdgcn_global_load_lds(AS1(Wxh+goffB), AS3(Bs +idx*8), 16, 0, 0);
      __builtin_amdgcn_global_load_lds(AS1(Wxl+goffB), AS3(BsL+idx*8), 16, 0, 0);
    }
    __syncthreads();

    short8 ah[4], al[4], bh[4], bl[4];
    #pragma unroll
    for (int f=0; f<4; ++f) {
      ah[f] = *(const short8*)&As [(wr*64+f*16+fr)*32 + rc];
      al[f] = *(const short8*)&AsL[(wr*64+f*16+fr)*32 + rc];
      bh[f] = *(const short8*)&Bs [(wc*64+f*16+fr)*32 + rc];
      bl[f] = *(const short8*)&BsL[(wc*64+f*16+fr)*32 + rc];
    }
    #pragma unroll
    for (int fi=0; fi<4; ++fi)
      #pragma unroll
      for (int fj=0; fj<4; ++fj) {
        acc[fi][fj] = __builtin_amdgcn_mfma_f32_16x16x32_bf16(ah[fi], bh[fj], acc[fi][fj], 0,0,0);
        acc[fi][fj] = __builtin_amdgcn_mfma_f32_16x16x32_bf16(ah[fi], bl[fj], acc[fi][fj], 0,0,0);
        acc[fi][fj] = __builtin_amdgcn_mfma_f32_16x16x32_bf16(al[fi], bh[fj], acc[fi][fj], 0,0,0);
      }
    __syncthreads();
  }

  #pragma unroll
  for (int fi=0; fi<4; ++fi)
    #pragma unroll
    for (int fj=0; fj<4; ++fj)
      #pragma unroll
      for (int r=0; r<4; ++r) {
        int row = m0 + wr*64 + fi*16 + (lane>>4)*4 + r;   // t*16 + b
        int col = n0 + wc*64 + fj*16 + (lane&15);
        vxout[(size_t)row*DIM + col] = acc[fi][fj][r] + b_v[col];
      }
}

// ---------- fused alpha+delta GEMM: one A-stage, two B-tiles, 32 MFMA/K-step.
// Writes ONE u32 {f16 a | f16 d<<16} per element (clean coalesced, no RMW).
__global__ __launch_bounds__(256) void gemm_ad_kernel(
    const ushort* __restrict__ Xh,
    const ushort* __restrict__ Wah, const ushort* __restrict__ Wdh,
    const float* __restrict__ b_a, const float* __restrict__ b_d,
    uint* __restrict__ adout)
{
  __shared__ ushort As[128*32];
  __shared__ ushort Ba[128*32];
  __shared__ ushort Bd[128*32];

  const int tid  = threadIdx.x;
  const int lane = tid & 63;
  const int wid  = tid >> 6;
  const int wr   = wid >> 1, wc = wid & 1;

  const int did = blockIdx.y * 8 + blockIdx.x;
  const int xcd = did & 7;
  const int j   = did >> 3;
  const int m0  = (xcd * 16 + (j >> 3)) * 128;
  const int n0  = (j & 7) * 128;

  f32x4 aca[4][4], acd[4][4];
  #pragma unroll
  for (int i=0;i<4;++i)
    #pragma unroll
    for (int jj=0;jj<4;++jj) {
      aca[i][jj] = f32x4{0.f,0.f,0.f,0.f};
      acd[i][jj] = f32x4{0.f,0.f,0.f,0.f};
    }

  const int fr = lane & 15;
  const int rc = (((lane >> 4) ^ ((fr >> 1) & 3))) * 8;

  for (int ks = 0; ks < DIM/32; ++ks) {
    const int k0 = ks*32;
    #pragma unroll
    for (int jl = 0; jl < 2; ++jl) {
      int idx = jl*256 + tid;
      int row = idx >> 2;
      int cs  = ((idx & 3) ^ ((row >> 1) & 3)) * 8;
      size_t goffA = (size_t)(m0+row)*DIM + k0 + cs;
      size_t goffB = (size_t)(n0+row)*DIM + k0 + cs;
      __builtin_amdgcn_global_load_lds(AS1(Xh+goffA),  AS3(As+idx*8), 16, 0, 0);
      __builtin_amdgcn_global_load_lds(AS1(Wah+goffB), AS3(Ba+idx*8), 16, 0, 0);
      __builtin_amdgcn_global_load_lds(AS1(Wdh+goffB), AS3(Bd+idx*8), 16, 0, 0);
    }
    __syncthreads();

    short8 ah[4], ba[4], bd[4];
    #pragma unroll
    for (int f=0; f<4; ++f) {
      ah[f] = *(const short8*)&As[(wr*64+f*16+fr)*32 + rc];
      ba[f] = *(const short8*)&Ba[(wc*64+f*16+fr)*32 + rc];
      bd[f] = *(const short8*)&Bd[(wc*64+f*16+fr)*32 + rc];
    }
    #pragma unroll
    for (int fi=0; fi<4; ++fi)
      #pragma unroll
      for (int fj=0; fj<4; ++fj) {
        aca[fi][fj] = __builtin_amdgcn_mfma_f32_16x16x32_bf16(ah[fi], ba[fj], aca[fi][fj], 0,0,0);
        acd[fi][fj] = __builtin_amdgcn_mfma_f32_16x16x32_bf16(ah[fi], bd[fj], acd[fi][fj], 0,0,0);
      }
    __syncthreads();
  }

  #pragma unroll
  for (int fi=0; fi<4; ++fi)
    #pragma unroll
    for (int fj=0; fj<4; ++fj)
      #pragma unroll
      for (int r=0; r<4; ++r) {
        int row = m0 + wr*64 + fi*16 + (lane>>4)*4 + r;
        int col = n0 + wc*64 + fj*16 + (lane&15);
        float a_ = 1.f + softplusf(aca[fi][fj][r] + b_a[col]);
        float d_ = sigmoidf_(acd[fi][fj][r] + b_d[col]);
        adout[(size_t)row*DIM + col] = (uint)f2h(a_) | ((uint)f2h(d_) << 16);
      }
}

// ---------- output GEMM: outs = comp * silu(Hb @ Woh^T) ----------
__global__ __launch_bounds__(256) void gemm_out_kernel(
    const ushort* __restrict__ Ah, const ushort* __restrict__ Bh,
    const float* __restrict__ extra, float* __restrict__ C)
{
  __shared__ ushort As[128*32];
  __shared__ ushort Bs[128*32];

  const int tid  = threadIdx.x;
  const int lane = tid & 63;
  const int wid  = tid >> 6;
  const int wr   = wid >> 1, wc = wid & 1;

  const int did = blockIdx.y * 8 + blockIdx.x;
  const int xcd = did & 7;
  const int j   = did >> 3;
  const int m0  = (xcd * 16 + (j >> 3)) * 128;
  const int n0  = (j & 7) * 128;

  f32x4 acc[4][4];
  #pragma unroll
  for (int i=0;i<4;++i)
    #pragma unroll
    for (int jj=0;jj<4;++jj) acc[i][jj] = f32x4{0.f,0.f,0.f,0.f};

  const int fr = lane & 15;
  const int rc = (((lane >> 4) ^ ((fr >> 1) & 3))) * 8;

  for (int ks = 0; ks < DIM/32; ++ks) {
    const int k0 = ks*32;
    #pragma unroll
    for (int jl = 0; jl < 2; ++jl) {
      int idx = jl*256 + tid;
      int row = idx >> 2;
      int cs  = ((idx & 3) ^ ((row >> 1) & 3)) * 8;
      __builtin_amdgcn_global_load_lds(AS1(Ah+(size_t)(m0+row)*DIM + k0 + cs), AS3(As+idx*8), 16, 0, 0);
      __builtin_amdgcn_global_load_lds(AS1(Bh+(size_t)(n0+row)*DIM + k0 + cs), AS3(Bs+idx*8), 16, 0, 0);
    }
    __syncthreads();

    short8 ah[4], bh[4];
    #pragma unroll
    for (int f=0; f<4; ++f) {
      ah[f] = *(const short8*)&As[(wr*64+f*16+fr)*32 + rc];
      bh[f] = *(const short8*)&Bs[(wc*64+f*16+fr)*32 + rc];
    }
    #pragma unroll
    for (int fi=0; fi<4; ++fi)
      #pragma unroll
      for (int fj=0; fj<4; ++fj)
        acc[fi][fj] = __builtin_amdgcn_mfma_f32_16x16x32_bf16(ah[fi], bh[fj], acc[fi][fj], 0,0,0);
    __syncthreads();
  }

  #pragma unroll
  for (int fi=0; fi<4; ++fi)
    #pragma unroll
    for (int fj=0; fj<4; ++fj)
      #pragma unroll
      for (int r=0; r<4; ++r) {
        int row = m0 + wr*64 + fi*16 + (lane>>4)*4 + r;
        int col = n0 + wc*64 + fj*16 + (lane&15);
        float c = acc[fi][fj][r];
        C[(size_t)row*DIM + col] = extra[(size_t)row*DIM + col] * (c * sigmoidf_(c));
      }
}

// ---------- elementwise recurrence scan (16384 independent chains) ----------
// Two 4B streams/step: vx (f32) + {f16 a, f16 d} (u32). Double-buffered
// groups of G=16 with sched_barrier(0) fences (round-5-proven structure).
#define SCAN_STEP(vv, adb, t)                                                \
  {                                                                          \
    uint bits = (adb);                                                       \
    __half ha_, hd_;                                                         \
    *reinterpret_cast<ushort*>(&ha_) = (ushort)(bits & 0xFFFF);              \
    *reinterpret_cast<ushort*>(&hd_) = (ushort)(bits >> 16);                 \
    float a = __half2float(ha_);                                             \
    float d = __half2float(hd_);                                             \
    float v = fmaf(r, h, (vv));                                              \
    float av = fminf(fmaxf(fabsf(v), 1e-6f), 10.0f);                         \
    float cand = copysignf(__builtin_amdgcn_exp2f(a * __builtin_amdgcn_logf(av)), v); \
    h = fmaf(d, cand - h, h);                                                \
    hout[(size_t)((t)+1)*BD + tid] = h;                                      \
    Hb[(size_t)(t)*BD + tid] = f2b(h);                                       \
  }

__global__ __launch_bounds__(64) void scan_kernel(
    const float* __restrict__ pv, const uint* __restrict__ pad,
    const float* __restrict__ rh, const float* __restrict__ h0,
    float* __restrict__ hout, ushort* __restrict__ Hb)
{
  int tid = blockIdx.x*64 + threadIdx.x;   // 0..16383 == b*DIM+e
  float r = rh[tid & (DIM-1)];
  float h = h0[tid];
  hout[tid] = h;                            // h[0] = h0

  float bufVA[G], bufVB[G];
  uint  bufDA[G], bufDB[G];

  #pragma unroll
  for (int i = 0; i < G; ++i) {
    bufVA[i] = pv [(size_t)i*BD + tid];
    bufDA[i] = pad[(size_t)i*BD + tid];
  }
  __builtin_amdgcn_sched_barrier(0);

  for (int gp = 0; gp < NG; gp += 2) {
    #pragma unroll
    for (int i = 0; i < G; ++i) {
      bufVB[i] = pv [(size_t)((gp+1)*G + i)*BD + tid];
      bufDB[i] = pad[(size_t)((gp+1)*G + i)*BD + tid];
    }
    __builtin_amdgcn_sched_barrier(0);
    #pragma unroll
    for (int i = 0; i < G; ++i) { SCAN_STEP(bufVA[i], bufDA[i], gp*G + i); }
    __builtin_amdgcn_sched_barrier(0);
    if (gp + 2 < NG) {
      #pragma unroll
      for (int i = 0; i < G; ++i) {
        bufVA[i] = pv [(size_t)((gp+2)*G + i)*BD + tid];
        bufDA[i] = pad[(size_t)((gp+2)*G + i)*BD + tid];
      }
    }
    __builtin_amdgcn_sched_barrier(0);
    #pragma unroll
    for (int i = 0; i < G; ++i) { SCAN_STEP(bufVB[i], bufDB[i], (gp+1)*G + i); }
    __builtin_amdgcn_sched_barrier(0);
  }
}

// ---------- compete softmax over contiguous groups of 32 ----------
__global__ __launch_bounds__(256) void compete_kernel(
    const float* __restrict__ h, float* __restrict__ comp)
{
  int g = blockIdx.x*256 + threadIdx.x;     // 524288 groups
  const float4* p = (const float4*)(h + (size_t)g*GSIZE);
  float vals[32];
  #pragma unroll
  for (int j = 0; j < 8; ++j) {
    float4 t4 = p[j];
    vals[4*j+0]=t4.x; vals[4*j+1]=t4.y; vals[4*j+2]=t4.z; vals[4*j+3]=t4.w;
  }
  float m = vals[0];
  #pragma unroll
  for (int j = 1; j < 32; ++j) m = fmaxf(m, vals[j]);
  float s = 0.f;
  #pragma unroll
  for (int j = 0; j < 32; ++j) { vals[j] = expf(vals[j]-m); s += vals[j]; }
  float inv = 1.f/s;
  float4* o = (float4*)(comp + (size_t)g*GSIZE);
  #pragma unroll
  for (int j = 0; j < 8; ++j) {
    float4 t4; t4.x=vals[4*j]*inv; t4.y=vals[4*j+1]*inv; t4.z=vals[4*j+2]*inv; t4.w=vals[4*j+3]*inv;
    o[j] = t4;
  }
}

extern "C" void kernel_launch(void* const* d_in, const int* in_sizes, int n_in,
                              void* d_out, int out_size, void* d_ws, size_t ws_size,
                              hipStream_t stream) {
  const float* x       = (const float*)d_in[0];
  const float* h0      = (const float*)d_in[1];
  const float* W_x     = (const float*)d_in[2];
  const float* r_h     = (const float*)d_in[3];
  const float* b       = (const float*)d_in[4];
  const float* W_alpha = (const float*)d_in[5];
  const float* b_alpha = (const float*)d_in[6];
  const float* W_delta = (const float*)d_in[7];
  const float* b_delta = (const float*)d_in[8];
  const float* W_out   = (const float*)d_in[9];

  float* out   = (float*)d_out;
  float* h_out = out;                                   // (T+1)*B*D
  float* outs  = out + (size_t)(TT+1)*BD;               // T*B*D

  char* p = (char*)d_ws;
  ushort* Xh  = (ushort*)p; p += (size_t)MROWS*DIM*2;   // 32MB
  ushort* Xl  = (ushort*)p; p += (size_t)MROWS*DIM*2;   // 32MB
  ushort* Wxh = (ushort*)p; p += (size_t)DIM*DIM*2;
  ushort* Wxl = (ushort*)p; p += (size_t)DIM*DIM*2;
  ushort* Wah = (ushort*)p; p += (size_t)DIM*DIM*2;
  ushort* Wdh = (ushort*)p; p += (size_t)DIM*DIM*2;
  ushort* Woh = (ushort*)p; p += (size_t)DIM*DIM*2;
  float*  vxa = (float*)p;  p += (size_t)MROWS*DIM*4;   // 64MB
  uint*   ada = (uint*)p;   p += (size_t)MROWS*DIM*4;   // 64MB
  ushort* Hb  = (ushort*)p; p += (size_t)MROWS*DIM*2;   // 32MB
  float*  comp = (float*)p; p += (size_t)MROWS*DIM*4;   // 64MB

  split_x_kernel<<<2048, 256, 0, stream>>>((const float4*)x, (ushort4*)Xh, (ushort4*)Xl, MROWS*DIM/4);
  split_w_kernel<<<1024, 256, 0, stream>>>((const float4*)W_x, (const float4*)W_alpha,
                                           (const float4*)W_delta, (const float4*)W_out,
                                           (ushort4*)Wxh, (ushort4*)Wxl, (ushort4*)Wah,
                                           (ushort4*)Wdh, (ushort4*)Woh, DIM*DIM/4);

  dim3 g(DIM/128, MROWS/128);
  gemm_vx_kernel<<<g, 256, 0, stream>>>(Xh, Xl, Wxh, Wxl, b, vxa);
  gemm_ad_kernel<<<g, 256, 0, stream>>>(Xh, Wah, Wdh, b_alpha, b_delta, ada);

  scan_kernel<<<256, 64, 0, stream>>>(vxa, ada, r_h, h0, h_out, Hb);

  compete_kernel<<<2048, 256, 0, stream>>>(h_out + (size_t)BD, comp);

  gemm_out_kernel<<<g, 256, 0, stream>>>(Hb, Woh, comp, outs);
}

// Round 8
// 605.535 us; speedup vs baseline: 1.4936x; 1.4936x over previous
//
#include <hip/hip_runtime.h>
#include <hip/hip_bf16.h>
#include <hip/hip_fp16.h>

#define DIM 1024
#define NGROUPS 32
#define GSIZE 32
#define TT 1024
#define BB 16
#define MROWS (TT*BB)          // 16384 rows for all batched GEMMs
#define BD (BB*DIM)            // 16384 elems per timestep slab
#define G 16                   // scan group size (steps per reg buffer)
#define NG (TT/G)              // 64 groups (even)

typedef __attribute__((ext_vector_type(8))) short short8;
typedef __attribute__((ext_vector_type(4))) float f32x4;

// ---------- helpers ----------
__device__ __forceinline__ ushort f2b(float v) {
  __hip_bfloat16 b = __float2bfloat16(v);
  return *reinterpret_cast<ushort*>(&b);
}
__device__ __forceinline__ float b2f(ushort u) {
  __hip_bfloat16 b; *reinterpret_cast<ushort*>(&b) = u;
  return __bfloat162float(b);
}
__device__ __forceinline__ ushort f2h(float v) {
  __half h = __float2half(v);
  return *reinterpret_cast<ushort*>(&h);
}
__device__ __forceinline__ float softplusf(float z) {
  return (z > 20.f) ? z : log1pf(expf(z));
}
__device__ __forceinline__ float sigmoidf_(float z) { return 1.f/(1.f+expf(-z)); }

#define AS1(p) ((__attribute__((address_space(1))) void*)(void*)(p))
#define AS3(p) ((__attribute__((address_space(3))) void*)(void*)(p))

// ---------- split x into bf16 hi/lo ----------
__global__ __launch_bounds__(256) void split_x_kernel(
    const float4* __restrict__ x, ushort4* __restrict__ xh, ushort4* __restrict__ xl, int n4) {
  int i = blockIdx.x*256 + threadIdx.x;
  int stride = gridDim.x*256;
  for (; i < n4; i += stride) {
    float4 v = x[i];
    ushort4 h, l;
    h.x = f2b(v.x); l.x = f2b(v.x - b2f(h.x));
    h.y = f2b(v.y); l.y = f2b(v.y - b2f(h.y));
    h.z = f2b(v.z); l.z = f2b(v.z - b2f(h.z));
    h.w = f2b(v.w); l.w = f2b(v.w - b2f(h.w));
    xh[i] = h; xl[i] = l;
  }
}

// ---------- split/convert weights ----------
__global__ __launch_bounds__(256) void split_w_kernel(
    const float4* __restrict__ wx, const float4* __restrict__ wa,
    const float4* __restrict__ wd, const float4* __restrict__ wo,
    ushort4* __restrict__ wxh, ushort4* __restrict__ wxl,
    ushort4* __restrict__ wah, ushort4* __restrict__ wdh,
    ushort4* __restrict__ woh, int n4) {
  int i = blockIdx.x*256 + threadIdx.x;
  if (i >= n4) return;
  float4 v = wx[i];
  ushort4 h, l;
  h.x = f2b(v.x); l.x = f2b(v.x - b2f(h.x));
  h.y = f2b(v.y); l.y = f2b(v.y - b2f(h.y));
  h.z = f2b(v.z); l.z = f2b(v.z - b2f(h.z));
  h.w = f2b(v.w); l.w = f2b(v.w - b2f(h.w));
  wxh[i] = h; wxl[i] = l;
  float4 a = wa[i];
  ushort4 ha; ha.x=f2b(a.x); ha.y=f2b(a.y); ha.z=f2b(a.z); ha.w=f2b(a.w);
  wah[i] = ha;
  float4 d = wd[i];
  ushort4 hd; hd.x=f2b(d.x); hd.y=f2b(d.y); hd.z=f2b(d.z); hd.w=f2b(d.w);
  wdh[i] = hd;
  float4 o = wo[i];
  ushort4 ho; ho.x=f2b(o.x); ho.y=f2b(o.y); ho.z=f2b(o.z); ho.w=f2b(o.w);
  woh[i] = ho;
}

// LDS chunk swizzle (verified r7: 0 bank conflicts): s(row)=(row>>1)&3;
// linear LDS dest, inverse-swizzled SOURCE, swizzled READ (rule 21).
// All GEMMs: 2-phase double-buffered LDS (catalog T3-minimum): stage tile
// k+1 BEFORE computing tile k; one vmcnt-drain barrier (__syncthreads) per
// K-step -> exposed stall = max(0, HBM latency - compute), not their sum.

// ---------- vx GEMM: vx = X @ Wx^T + b  (split-bf16 3-term, ~fp32 accurate) ----------
__global__ __launch_bounds__(256, 2) void gemm_vx_kernel(
    const ushort* __restrict__ Xh, const ushort* __restrict__ Xl,
    const ushort* __restrict__ Wxh, const ushort* __restrict__ Wxl,
    const float* __restrict__ b_v, float* __restrict__ vxout)
{
  __shared__ ushort As [2][128*32];
  __shared__ ushort AsL[2][128*32];
  __shared__ ushort Bs [2][128*32];
  __shared__ ushort BsL[2][128*32];

  const int tid  = threadIdx.x;
  const int lane = tid & 63;
  const int wid  = tid >> 6;
  const int wr   = wid >> 1, wc = wid & 1;

  const int did = blockIdx.y * 8 + blockIdx.x;
  const int xcd = did & 7;
  const int j   = did >> 3;
  const int m0  = (xcd * 16 + (j >> 3)) * 128;
  const int n0  = (j & 7) * 128;

  f32x4 acc[4][4];
  #pragma unroll
  for (int i=0;i<4;++i)
    #pragma unroll
    for (int jj=0;jj<4;++jj) acc[i][jj] = f32x4{0.f,0.f,0.f,0.f};

  const int fr = lane & 15;
  const int rc = (((lane >> 4) ^ ((fr >> 1) & 3))) * 8;

#define STAGE_VX(cur, ks)                                                     \
  {                                                                           \
    _Pragma("unroll")                                                         \
    for (int jl = 0; jl < 2; ++jl) {                                          \
      int idx = jl*256 + tid;                                                 \
      int row = idx >> 2;                                                     \
      int cs  = ((idx & 3) ^ ((row >> 1) & 3)) * 8;                           \
      size_t gA = (size_t)(m0+row)*DIM + (ks)*32 + cs;                        \
      size_t gB = (size_t)(n0+row)*DIM + (ks)*32 + cs;                        \
      __builtin_amdgcn_global_load_lds(AS1(Xh+gA),  AS3(&As [cur][idx*8]), 16, 0, 0); \
      __builtin_amdgcn_global_load_lds(AS1(Xl+gA),  AS3(&AsL[cur][idx*8]), 16, 0, 0); \
      __builtin_amdgcn_global_load_lds(AS1(Wxh+gB), AS3(&Bs [cur][idx*8]), 16, 0, 0); \
      __builtin_amdgcn_global_load_lds(AS1(Wxl+gB), AS3(&BsL[cur][idx*8]), 16, 0, 0); \
    }                                                                         \
  }

  STAGE_VX(0, 0);
  __syncthreads();
  int cur = 0;

  for (int ks = 0; ks < DIM/32; ++ks) {
    if (ks + 1 < DIM/32) STAGE_VX(cur^1, ks+1);
    __builtin_amdgcn_sched_barrier(0);

    short8 ah[4], al[4], bh[4], bl[4];
    #pragma unroll
    for (int f=0; f<4; ++f) {
      ah[f] = *(const short8*)&As [cur][(wr*64+f*16+fr)*32 + rc];
      al[f] = *(const short8*)&AsL[cur][(wr*64+f*16+fr)*32 + rc];
      bh[f] = *(const short8*)&Bs [cur][(wc*64+f*16+fr)*32 + rc];
      bl[f] = *(const short8*)&BsL[cur][(wc*64+f*16+fr)*32 + rc];
    }
    #pragma unroll
    for (int fi=0; fi<4; ++fi)
      #pragma unroll
      for (int fj=0; fj<4; ++fj) {
        acc[fi][fj] = __builtin_amdgcn_mfma_f32_16x16x32_bf16(ah[fi], bh[fj], acc[fi][fj], 0,0,0);
        acc[fi][fj] = __builtin_amdgcn_mfma_f32_16x16x32_bf16(ah[fi], bl[fj], acc[fi][fj], 0,0,0);
        acc[fi][fj] = __builtin_amdgcn_mfma_f32_16x16x32_bf16(al[fi], bh[fj], acc[fi][fj], 0,0,0);
      }
    __syncthreads();
    cur ^= 1;
  }

  #pragma unroll
  for (int fi=0; fi<4; ++fi)
    #pragma unroll
    for (int fj=0; fj<4; ++fj)
      #pragma unroll
      for (int r=0; r<4; ++r) {
        int row = m0 + wr*64 + fi*16 + (lane>>4)*4 + r;   // t*16 + b
        int col = n0 + wc*64 + fj*16 + (lane&15);
        vxout[(size_t)row*DIM + col] = acc[fi][fj][r] + b_v[col];
      }
}

// ---------- fused alpha+delta GEMM: one A-stage, two B-tiles, 32 MFMA/K-step.
__global__ __launch_bounds__(256, 2) void gemm_ad_kernel(
    const ushort* __restrict__ Xh,
    const ushort* __restrict__ Wah, const ushort* __restrict__ Wdh,
    const float* __restrict__ b_a, const float* __restrict__ b_d,
    uint* __restrict__ adout)
{
  __shared__ ushort As[2][128*32];
  __shared__ ushort Ba[2][128*32];
  __shared__ ushort Bd[2][128*32];

  const int tid  = threadIdx.x;
  const int lane = tid & 63;
  const int wid  = tid >> 6;
  const int wr   = wid >> 1, wc = wid & 1;

  const int did = blockIdx.y * 8 + blockIdx.x;
  const int xcd = did & 7;
  const int j   = did >> 3;
  const int m0  = (xcd * 16 + (j >> 3)) * 128;
  const int n0  = (j & 7) * 128;

  f32x4 aca[4][4], acd[4][4];
  #pragma unroll
  for (int i=0;i<4;++i)
    #pragma unroll
    for (int jj=0;jj<4;++jj) {
      aca[i][jj] = f32x4{0.f,0.f,0.f,0.f};
      acd[i][jj] = f32x4{0.f,0.f,0.f,0.f};
    }

  const int fr = lane & 15;
  const int rc = (((lane >> 4) ^ ((fr >> 1) & 3))) * 8;

#define STAGE_AD(cur, ks)                                                     \
  {                                                                           \
    _Pragma("unroll")                                                         \
    for (int jl = 0; jl < 2; ++jl) {                                          \
      int idx = jl*256 + tid;                                                 \
      int row = idx >> 2;                                                     \
      int cs  = ((idx & 3) ^ ((row >> 1) & 3)) * 8;                           \
      size_t gA = (size_t)(m0+row)*DIM + (ks)*32 + cs;                        \
      size_t gB = (size_t)(n0+row)*DIM + (ks)*32 + cs;                        \
      __builtin_amdgcn_global_load_lds(AS1(Xh+gA),  AS3(&As[cur][idx*8]), 16, 0, 0); \
      __builtin_amdgcn_global_load_lds(AS1(Wah+gB), AS3(&Ba[cur][idx*8]), 16, 0, 0); \
      __builtin_amdgcn_global_load_lds(AS1(Wdh+gB), AS3(&Bd[cur][idx*8]), 16, 0, 0); \
    }                                                                         \
  }

  STAGE_AD(0, 0);
  __syncthreads();
  int cur = 0;

  for (int ks = 0; ks < DIM/32; ++ks) {
    if (ks + 1 < DIM/32) STAGE_AD(cur^1, ks+1);
    __builtin_amdgcn_sched_barrier(0);

    short8 ah[4], ba[4], bd[4];
    #pragma unroll
    for (int f=0; f<4; ++f) {
      ah[f] = *(const short8*)&As[cur][(wr*64+f*16+fr)*32 + rc];
      ba[f] = *(const short8*)&Ba[cur][(wc*64+f*16+fr)*32 + rc];
      bd[f] = *(const short8*)&Bd[cur][(wc*64+f*16+fr)*32 + rc];
    }
    #pragma unroll
    for (int fi=0; fi<4; ++fi)
      #pragma unroll
      for (int fj=0; fj<4; ++fj) {
        aca[fi][fj] = __builtin_amdgcn_mfma_f32_16x16x32_bf16(ah[fi], ba[fj], aca[fi][fj], 0,0,0);
        acd[fi][fj] = __builtin_amdgcn_mfma_f32_16x16x32_bf16(ah[fi], bd[fj], acd[fi][fj], 0,0,0);
      }
    __syncthreads();
    cur ^= 1;
  }

  #pragma unroll
  for (int fi=0; fi<4; ++fi)
    #pragma unroll
    for (int fj=0; fj<4; ++fj)
      #pragma unroll
      for (int r=0; r<4; ++r) {
        int row = m0 + wr*64 + fi*16 + (lane>>4)*4 + r;
        int col = n0 + wc*64 + fj*16 + (lane&15);
        float a_ = 1.f + softplusf(aca[fi][fj][r] + b_a[col]);
        float d_ = sigmoidf_(acd[fi][fj][r] + b_d[col]);
        adout[(size_t)row*DIM + col] = (uint)f2h(a_) | ((uint)f2h(d_) << 16);
      }
}

// ---------- output GEMM: outs = comp * silu(Hb @ Woh^T) ----------
__global__ __launch_bounds__(256, 2) void gemm_out_kernel(
    const ushort* __restrict__ Ah, const ushort* __restrict__ Bh,
    const float* __restrict__ extra, float* __restrict__ C)
{
  __shared__ ushort As[2][128*32];
  __shared__ ushort Bs[2][128*32];

  const int tid  = threadIdx.x;
  const int lane = tid & 63;
  const int wid  = tid >> 6;
  const int wr   = wid >> 1, wc = wid & 1;

  const int did = blockIdx.y * 8 + blockIdx.x;
  const int xcd = did & 7;
  const int j   = did >> 3;
  const int m0  = (xcd * 16 + (j >> 3)) * 128;
  const int n0  = (j & 7) * 128;

  f32x4 acc[4][4];
  #pragma unroll
  for (int i=0;i<4;++i)
    #pragma unroll
    for (int jj=0;jj<4;++jj) acc[i][jj] = f32x4{0.f,0.f,0.f,0.f};

  const int fr = lane & 15;
  const int rc = (((lane >> 4) ^ ((fr >> 1) & 3))) * 8;

#define STAGE_O(cur, ks)                                                      \
  {                                                                           \
    _Pragma("unroll")                                                         \
    for (int jl = 0; jl < 2; ++jl) {                                          \
      int idx = jl*256 + tid;                                                 \
      int row = idx >> 2;                                                     \
      int cs  = ((idx & 3) ^ ((row >> 1) & 3)) * 8;                           \
      __builtin_amdgcn_global_load_lds(AS1(Ah+(size_t)(m0+row)*DIM + (ks)*32 + cs), AS3(&As[cur][idx*8]), 16, 0, 0); \
      __builtin_amdgcn_global_load_lds(AS1(Bh+(size_t)(n0+row)*DIM + (ks)*32 + cs), AS3(&Bs[cur][idx*8]), 16, 0, 0); \
    }                                                                         \
  }

  STAGE_O(0, 0);
  __syncthreads();
  int cur = 0;

  for (int ks = 0; ks < DIM/32; ++ks) {
    if (ks + 1 < DIM/32) STAGE_O(cur^1, ks+1);
    __builtin_amdgcn_sched_barrier(0);

    short8 ah[4], bh[4];
    #pragma unroll
    for (int f=0; f<4; ++f) {
      ah[f] = *(const short8*)&As[cur][(wr*64+f*16+fr)*32 + rc];
      bh[f] = *(const short8*)&Bs[cur][(wc*64+f*16+fr)*32 + rc];
    }
    #pragma unroll
    for (int fi=0; fi<4; ++fi)
      #pragma unroll
      for (int fj=0; fj<4; ++fj)
        acc[fi][fj] = __builtin_amdgcn_mfma_f32_16x16x32_bf16(ah[fi], bh[fj], acc[fi][fj], 0,0,0);
    __syncthreads();
    cur ^= 1;
  }

  #pragma unroll
  for (int fi=0; fi<4; ++fi)
    #pragma unroll
    for (int fj=0; fj<4; ++fj)
      #pragma unroll
      for (int r=0; r<4; ++r) {
        int row = m0 + wr*64 + fi*16 + (lane>>4)*4 + r;
        int col = n0 + wc*64 + fj*16 + (lane&15);
        float c = acc[fi][fj][r];
        C[(size_t)row*DIM + col] = extra[(size_t)row*DIM + col] * (c * sigmoidf_(c));
      }
}

// ---------- elementwise recurrence scan (16384 independent chains) ----------
#define SCAN_STEP(vv, adb, t)                                                \
  {                                                                          \
    uint bits = (adb);                                                       \
    __half ha_, hd_;                                                         \
    *reinterpret_cast<ushort*>(&ha_) = (ushort)(bits & 0xFFFF);              \
    *reinterpret_cast<ushort*>(&hd_) = (ushort)(bits >> 16);                 \
    float a = __half2float(ha_);                                             \
    float d = __half2float(hd_);                                             \
    float v = fmaf(r, h, (vv));                                              \
    float av = fminf(fmaxf(fabsf(v), 1e-6f), 10.0f);                         \
    float cand = copysignf(__builtin_amdgcn_exp2f(a * __builtin_amdgcn_logf(av)), v); \
    h = fmaf(d, cand - h, h);                                                \
    hout[(size_t)((t)+1)*BD + tid] = h;                                      \
    Hb[(size_t)(t)*BD + tid] = f2b(h);                                       \
  }

__global__ __launch_bounds__(64) void scan_kernel(
    const float* __restrict__ pv, const uint* __restrict__ pad,
    const float* __restrict__ rh, const float* __restrict__ h0,
    float* __restrict__ hout, ushort* __restrict__ Hb)
{
  int tid = blockIdx.x*64 + threadIdx.x;   // 0..16383 == b*DIM+e
  float r = rh[tid & (DIM-1)];
  float h = h0[tid];
  hout[tid] = h;                            // h[0] = h0

  float bufVA[G], bufVB[G];
  uint  bufDA[G], bufDB[G];

  #pragma unroll
  for (int i = 0; i < G; ++i) {
    bufVA[i] = pv [(size_t)i*BD + tid];
    bufDA[i] = pad[(size_t)i*BD + tid];
  }
  __builtin_amdgcn_sched_barrier(0);

  for (int gp = 0; gp < NG; gp += 2) {
    #pragma unroll
    for (int i = 0; i < G; ++i) {
      bufVB[i] = pv [(size_t)((gp+1)*G + i)*BD + tid];
      bufDB[i] = pad[(size_t)((gp+1)*G + i)*BD + tid];
    }
    __builtin_amdgcn_sched_barrier(0);
    #pragma unroll
    for (int i = 0; i < G; ++i) { SCAN_STEP(bufVA[i], bufDA[i], gp*G + i); }
    __builtin_amdgcn_sched_barrier(0);
    if (gp + 2 < NG) {
      #pragma unroll
      for (int i = 0; i < G; ++i) {
        bufVA[i] = pv [(size_t)((gp+2)*G + i)*BD + tid];
        bufDA[i] = pad[(size_t)((gp+2)*G + i)*BD + tid];
      }
    }
    __builtin_amdgcn_sched_barrier(0);
    #pragma unroll
    for (int i = 0; i < G; ++i) { SCAN_STEP(bufVB[i], bufDB[i], (gp+1)*G + i); }
    __builtin_amdgcn_sched_barrier(0);
  }
}

// ---------- compete softmax over contiguous groups of 32 ----------
__global__ __launch_bounds__(256) void compete_kernel(
    const float* __restrict__ h, float* __restrict__ comp)
{
  int g = blockIdx.x*256 + threadIdx.x;     // 524288 groups
  const float4* p = (const float4*)(h + (size_t)g*GSIZE);
  float vals[32];
  #pragma unroll
  for (int j = 0; j < 8; ++j) {
    float4 t4 = p[j];
    vals[4*j+0]=t4.x; vals[4*j+1]=t4.y; vals[4*j+2]=t4.z; vals[4*j+3]=t4.w;
  }
  float m = vals[0];
  #pragma unroll
  for (int j = 1; j < 32; ++j) m = fmaxf(m, vals[j]);
  float s = 0.f;
  #pragma unroll
  for (int j = 0; j < 32; ++j) { vals[j] = expf(vals[j]-m); s += vals[j]; }
  float inv = 1.f/s;
  float4* o = (float4*)(comp + (size_t)g*GSIZE);
  #pragma unroll
  for (int j = 0; j < 8; ++j) {
    float4 t4; t4.x=vals[4*j]*inv; t4.y=vals[4*j+1]*inv; t4.z=vals[4*j+2]*inv; t4.w=vals[4*j+3]*inv;
    o[j] = t4;
  }
}

extern "C" void kernel_launch(void* const* d_in, const int* in_sizes, int n_in,
                              void* d_out, int out_size, void* d_ws, size_t ws_size,
                              hipStream_t stream) {
  const float* x       = (const float*)d_in[0];
  const float* h0      = (const float*)d_in[1];
  const float* W_x     = (const float*)d_in[2];
  const float* r_h     = (const float*)d_in[3];
  const float* b       = (const float*)d_in[4];
  const float* W_alpha = (const float*)d_in[5];
  const float* b_alpha = (const float*)d_in[6];
  const float* W_delta = (const float*)d_in[7];
  const float* b_delta = (const float*)d_in[8];
  const float* W_out   = (const float*)d_in[9];

  float* out   = (float*)d_out;
  float* h_out = out;                                   // (T+1)*B*D
  float* outs  = out + (size_t)(TT+1)*BD;               // T*B*D

  char* p = (char*)d_ws;
  ushort* Xh  = (ushort*)p; p += (size_t)MROWS*DIM*2;   // 32MB
  ushort* Xl  = (ushort*)p; p += (size_t)MROWS*DIM*2;   // 32MB
  ushort* Wxh = (ushort*)p; p += (size_t)DIM*DIM*2;
  ushort* Wxl = (ushort*)p; p += (size_t)DIM*DIM*2;
  ushort* Wah = (ushort*)p; p += (size_t)DIM*DIM*2;
  ushort* Wdh = (ushort*)p; p += (size_t)DIM*DIM*2;
  ushort* Woh = (ushort*)p; p += (size_t)DIM*DIM*2;
  float*  vxa = (float*)p;  p += (size_t)MROWS*DIM*4;   // 64MB
  uint*   ada = (uint*)p;   p += (size_t)MROWS*DIM*4;   // 64MB
  ushort* Hb  = (ushort*)p; p += (size_t)MROWS*DIM*2;   // 32MB
  float*  comp = (float*)p; p += (size_t)MROWS*DIM*4;   // 64MB

  split_x_kernel<<<2048, 256, 0, stream>>>((const float4*)x, (ushort4*)Xh, (ushort4*)Xl, MROWS*DIM/4);
  split_w_kernel<<<1024, 256, 0, stream>>>((const float4*)W_x, (const float4*)W_alpha,
                                           (const float4*)W_delta, (const float4*)W_out,
                                           (ushort4*)Wxh, (ushort4*)Wxl, (ushort4*)Wah,
                                           (ushort4*)Wdh, (ushort4*)Woh, DIM*DIM/4);

  dim3 g(DIM/128, MROWS/128);
  gemm_vx_kernel<<<g, 256, 0, stream>>>(Xh, Xl, Wxh, Wxl, b, vxa);
  gemm_ad_kernel<<<g, 256, 0, stream>>>(Xh, Wah, Wdh, b_alpha, b_delta, ada);

  scan_kernel<<<256, 64, 0, stream>>>(vxa, ada, r_h, h0, h_out, Hb);

  compete_kernel<<<2048, 256, 0, stream>>>(h_out + (size_t)BD, comp);

  gemm_out_kernel<<<g, 256, 0, stream>>>(Hb, Woh, comp, outs);
}

// Round 9
// 559.470 us; speedup vs baseline: 1.6166x; 1.0823x over previous
//
#include <hip/hip_runtime.h>
#include <hip/hip_bf16.h>
#include <hip/hip_fp16.h>

#define DIM 1024
#define NGROUPS 32
#define GSIZE 32
#define TT 1024
#define BB 16
#define MROWS (TT*BB)          // 16384 rows for all batched GEMMs
#define BD (BB*DIM)            // 16384 elems per timestep slab
#define G 16                   // scan group size (steps per reg buffer)
#define NG (TT/G)              // 64 groups (even)

typedef __attribute__((ext_vector_type(8))) _Float16 half8;
typedef __attribute__((ext_vector_type(4))) float f32x4;

// ---------- helpers ----------
__device__ __forceinline__ ushort f2h(float v) {
  __half h = __float2half(v);
  return *reinterpret_cast<ushort*>(&h);
}
__device__ __forceinline__ float softplusf(float z) {
  return (z > 20.f) ? z : log1pf(expf(z));
}
__device__ __forceinline__ float sigmoidf_(float z) { return 1.f/(1.f+expf(-z)); }

#define AS1(p) ((__attribute__((address_space(1))) void*)(void*)(p))
#define AS3(p) ((__attribute__((address_space(3))) void*)(void*)(p))

// ---------- convert x to f16 ----------
__global__ __launch_bounds__(256) void split_x_kernel(
    const float4* __restrict__ x, ushort4* __restrict__ xf, int n4) {
  int i = blockIdx.x*256 + threadIdx.x;
  int stride = gridDim.x*256;
  for (; i < n4; i += stride) {
    float4 v = x[i];
    ushort4 h;
    h.x = f2h(v.x); h.y = f2h(v.y); h.z = f2h(v.z); h.w = f2h(v.w);
    xf[i] = h;
  }
}

// ---------- convert weights to f16 ----------
__global__ __launch_bounds__(256) void split_w_kernel(
    const float4* __restrict__ wx, const float4* __restrict__ wa,
    const float4* __restrict__ wd, const float4* __restrict__ wo,
    ushort4* __restrict__ wxf, ushort4* __restrict__ waf,
    ushort4* __restrict__ wdf, ushort4* __restrict__ wof, int n4) {
  int i = blockIdx.x*256 + threadIdx.x;
  if (i >= n4) return;
  float4 v = wx[i];
  ushort4 h; h.x=f2h(v.x); h.y=f2h(v.y); h.z=f2h(v.z); h.w=f2h(v.w);
  wxf[i] = h;
  float4 a = wa[i];
  ushort4 ha; ha.x=f2h(a.x); ha.y=f2h(a.y); ha.z=f2h(a.z); ha.w=f2h(a.w);
  waf[i] = ha;
  float4 d = wd[i];
  ushort4 hd; hd.x=f2h(d.x); hd.y=f2h(d.y); hd.z=f2h(d.z); hd.w=f2h(d.w);
  wdf[i] = hd;
  float4 o = wo[i];
  ushort4 ho; ho.x=f2h(o.x); ho.y=f2h(o.y); ho.z=f2h(o.z); ho.w=f2h(o.w);
  wof[i] = ho;
}

// LDS chunk swizzle (verified r7/r8: 0 bank conflicts): s(row)=(row>>1)&3;
// linear LDS dest, inverse-swizzled SOURCE, swizzled READ (rule 21).
// 2-phase double-buffer (verified r8: gemm_ad 405->154): stage k+1 before
// computing k; one drain barrier per K-step.

// ---------- vx GEMM: vx = X @ Wx^T + b  (f16 single-pass) ----------
// 256 thr, 128x128 tile, 4 waves 2x2, per-wave 64x64. (256,3): ~110 VGPR
// actual -> 4 blocks/CU; LDS 32KB.
__global__ __launch_bounds__(256, 3) void gemm_vx_kernel(
    const ushort* __restrict__ Xf, const ushort* __restrict__ Wxf,
    const float* __restrict__ b_v, float* __restrict__ vxout)
{
  __shared__ ushort As[2][128*32];
  __shared__ ushort Bs[2][128*32];

  const int tid  = threadIdx.x;
  const int lane = tid & 63;
  const int wid  = tid >> 6;
  const int wr   = wid >> 1, wc = wid & 1;

  const int did = blockIdx.y * 8 + blockIdx.x;
  const int xcd = did & 7;
  const int j   = did >> 3;
  const int m0  = (xcd * 16 + (j >> 3)) * 128;
  const int n0  = (j & 7) * 128;

  f32x4 acc[4][4];
  #pragma unroll
  for (int i=0;i<4;++i)
    #pragma unroll
    for (int jj=0;jj<4;++jj) acc[i][jj] = f32x4{0.f,0.f,0.f,0.f};

  const int fr = lane & 15;
  const int rc = (((lane >> 4) ^ ((fr >> 1) & 3))) * 8;

#define STAGE_VX(cur, ks)                                                     \
  {                                                                           \
    _Pragma("unroll")                                                         \
    for (int jl = 0; jl < 2; ++jl) {                                          \
      int idx = jl*256 + tid;                                                 \
      int row = idx >> 2;                                                     \
      int cs  = ((idx & 3) ^ ((row >> 1) & 3)) * 8;                           \
      size_t gA = (size_t)(m0+row)*DIM + (ks)*32 + cs;                        \
      size_t gB = (size_t)(n0+row)*DIM + (ks)*32 + cs;                        \
      __builtin_amdgcn_global_load_lds(AS1(Xf+gA),  AS3(&As[cur][idx*8]), 16, 0, 0); \
      __builtin_amdgcn_global_load_lds(AS1(Wxf+gB), AS3(&Bs[cur][idx*8]), 16, 0, 0); \
    }                                                                         \
  }

  STAGE_VX(0, 0);
  __syncthreads();
  int cur = 0;

  for (int ks = 0; ks < DIM/32; ++ks) {
    if (ks + 1 < DIM/32) STAGE_VX(cur^1, ks+1);
    __builtin_amdgcn_sched_barrier(0);

    half8 ah[4], bh[4];
    #pragma unroll
    for (int f=0; f<4; ++f) {
      ah[f] = *(const half8*)&As[cur][(wr*64+f*16+fr)*32 + rc];
      bh[f] = *(const half8*)&Bs[cur][(wc*64+f*16+fr)*32 + rc];
    }
    #pragma unroll
    for (int fi=0; fi<4; ++fi)
      #pragma unroll
      for (int fj=0; fj<4; ++fj)
        acc[fi][fj] = __builtin_amdgcn_mfma_f32_16x16x32_f16(ah[fi], bh[fj], acc[fi][fj], 0,0,0);
    __syncthreads();
    cur ^= 1;
  }

  #pragma unroll
  for (int fi=0; fi<4; ++fi)
    #pragma unroll
    for (int fj=0; fj<4; ++fj)
      #pragma unroll
      for (int r=0; r<4; ++r) {
        int row = m0 + wr*64 + fi*16 + (lane>>4)*4 + r;   // t*16 + b
        int col = n0 + wc*64 + fj*16 + (lane&15);
        vxout[(size_t)row*DIM + col] = acc[fi][fj][r] + b_v[col];
      }
}

// ---------- fused alpha+delta GEMM (f16): one A-stage, two B-tiles ----------
// 512 thr = 8 waves (4 row-groups x 2 col-groups), per-wave 32x128-of-2-outs:
// acc 2x4 x2 = 16 f32x4 = 64 VGPR. (512,2), LDS 48KB -> 12-16 waves/CU.
__global__ __launch_bounds__(512, 2) void gemm_ad_kernel(
    const ushort* __restrict__ Xf,
    const ushort* __restrict__ Waf, const ushort* __restrict__ Wdf,
    const float* __restrict__ b_a, const float* __restrict__ b_d,
    uint* __restrict__ adout)
{
  __shared__ ushort As[2][128*32];
  __shared__ ushort Ba[2][128*32];
  __shared__ ushort Bd[2][128*32];

  const int tid  = threadIdx.x;
  const int lane = tid & 63;
  const int wid  = tid >> 6;          // 0..7
  const int wr   = wid >> 1;          // 0..3 (32-row group)
  const int wc   = wid & 1;           // 0..1 (64-col group)

  const int did = blockIdx.y * 8 + blockIdx.x;
  const int xcd = did & 7;
  const int j   = did >> 3;
  const int m0  = (xcd * 16 + (j >> 3)) * 128;
  const int n0  = (j & 7) * 128;

  f32x4 aca[2][4], acd[2][4];
  #pragma unroll
  for (int i=0;i<2;++i)
    #pragma unroll
    for (int jj=0;jj<4;++jj) {
      aca[i][jj] = f32x4{0.f,0.f,0.f,0.f};
      acd[i][jj] = f32x4{0.f,0.f,0.f,0.f};
    }

  const int fr = lane & 15;
  const int rc = (((lane >> 4) ^ ((fr >> 1) & 3))) * 8;

#define STAGE_AD(cur, ks)                                                     \
  {                                                                           \
    int row = tid >> 2;                                                       \
    int cs  = ((tid & 3) ^ ((row >> 1) & 3)) * 8;                             \
    size_t gA = (size_t)(m0+row)*DIM + (ks)*32 + cs;                          \
    size_t gB = (size_t)(n0+row)*DIM + (ks)*32 + cs;                          \
    __builtin_amdgcn_global_load_lds(AS1(Xf+gA),  AS3(&As[cur][tid*8]), 16, 0, 0); \
    __builtin_amdgcn_global_load_lds(AS1(Waf+gB), AS3(&Ba[cur][tid*8]), 16, 0, 0); \
    __builtin_amdgcn_global_load_lds(AS1(Wdf+gB), AS3(&Bd[cur][tid*8]), 16, 0, 0); \
  }

  STAGE_AD(0, 0);
  __syncthreads();
  int cur = 0;

  for (int ks = 0; ks < DIM/32; ++ks) {
    if (ks + 1 < DIM/32) STAGE_AD(cur^1, ks+1);
    __builtin_amdgcn_sched_barrier(0);

    half8 ah[2], ba[4], bd[4];
    #pragma unroll
    for (int f=0; f<2; ++f)
      ah[f] = *(const half8*)&As[cur][(wr*32+f*16+fr)*32 + rc];
    #pragma unroll
    for (int f=0; f<4; ++f) {
      ba[f] = *(const half8*)&Ba[cur][(wc*64+f*16+fr)*32 + rc];
      bd[f] = *(const half8*)&Bd[cur][(wc*64+f*16+fr)*32 + rc];
    }
    #pragma unroll
    for (int fi=0; fi<2; ++fi)
      #pragma unroll
      for (int fj=0; fj<4; ++fj) {
        aca[fi][fj] = __builtin_amdgcn_mfma_f32_16x16x32_f16(ah[fi], ba[fj], aca[fi][fj], 0,0,0);
        acd[fi][fj] = __builtin_amdgcn_mfma_f32_16x16x32_f16(ah[fi], bd[fj], acd[fi][fj], 0,0,0);
      }
    __syncthreads();
    cur ^= 1;
  }

  #pragma unroll
  for (int fi=0; fi<2; ++fi)
    #pragma unroll
    for (int fj=0; fj<4; ++fj)
      #pragma unroll
      for (int r=0; r<4; ++r) {
        int row = m0 + wr*32 + fi*16 + (lane>>4)*4 + r;
        int col = n0 + wc*64 + fj*16 + fr;
        float a_ = 1.f + softplusf(aca[fi][fj][r] + b_a[col]);
        float d_ = sigmoidf_(acd[fi][fj][r] + b_d[col]);
        adout[(size_t)row*DIM + col] = (uint)f2h(a_) | ((uint)f2h(d_) << 16);
      }
}

// ---------- output GEMM: outs = comp * silu(Hh @ Wof^T)  (f16) ----------
__global__ __launch_bounds__(256, 3) void gemm_out_kernel(
    const ushort* __restrict__ Ah, const ushort* __restrict__ Bh,
    const float* __restrict__ extra, float* __restrict__ C)
{
  __shared__ ushort As[2][128*32];
  __shared__ ushort Bs[2][128*32];

  const int tid  = threadIdx.x;
  const int lane = tid & 63;
  const int wid  = tid >> 6;
  const int wr   = wid >> 1, wc = wid & 1;

  const int did = blockIdx.y * 8 + blockIdx.x;
  const int xcd = did & 7;
  const int j   = did >> 3;
  const int m0  = (xcd * 16 + (j >> 3)) * 128;
  const int n0  = (j & 7) * 128;

  f32x4 acc[4][4];
  #pragma unroll
  for (int i=0;i<4;++i)
    #pragma unroll
    for (int jj=0;jj<4;++jj) acc[i][jj] = f32x4{0.f,0.f,0.f,0.f};

  const int fr = lane & 15;
  const int rc = (((lane >> 4) ^ ((fr >> 1) & 3))) * 8;

#define STAGE_O(cur, ks)                                                      \
  {                                                                           \
    _Pragma("unroll")                                                         \
    for (int jl = 0; jl < 2; ++jl) {                                          \
      int idx = jl*256 + tid;                                                 \
      int row = idx >> 2;                                                     \
      int cs  = ((idx & 3) ^ ((row >> 1) & 3)) * 8;                           \
      __builtin_amdgcn_global_load_lds(AS1(Ah+(size_t)(m0+row)*DIM + (ks)*32 + cs), AS3(&As[cur][idx*8]), 16, 0, 0); \
      __builtin_amdgcn_global_load_lds(AS1(Bh+(size_t)(n0+row)*DIM + (ks)*32 + cs), AS3(&Bs[cur][idx*8]), 16, 0, 0); \
    }                                                                         \
  }

  STAGE_O(0, 0);
  __syncthreads();
  int cur = 0;

  for (int ks = 0; ks < DIM/32; ++ks) {
    if (ks + 1 < DIM/32) STAGE_O(cur^1, ks+1);
    __builtin_amdgcn_sched_barrier(0);

    half8 ah[4], bh[4];
    #pragma unroll
    for (int f=0; f<4; ++f) {
      ah[f] = *(const half8*)&As[cur][(wr*64+f*16+fr)*32 + rc];
      bh[f] = *(const half8*)&Bs[cur][(wc*64+f*16+fr)*32 + rc];
    }
    #pragma unroll
    for (int fi=0; fi<4; ++fi)
      #pragma unroll
      for (int fj=0; fj<4; ++fj)
        acc[fi][fj] = __builtin_amdgcn_mfma_f32_16x16x32_f16(ah[fi], bh[fj], acc[fi][fj], 0,0,0);
    __syncthreads();
    cur ^= 1;
  }

  #pragma unroll
  for (int fi=0; fi<4; ++fi)
    #pragma unroll
    for (int fj=0; fj<4; ++fj)
      #pragma unroll
      for (int r=0; r<4; ++r) {
        int row = m0 + wr*64 + fi*16 + (lane>>4)*4 + r;
        int col = n0 + wc*64 + fj*16 + (lane&15);
        float c = acc[fi][fj][r];
        C[(size_t)row*DIM + col] = extra[(size_t)row*DIM + col] * (c * sigmoidf_(c));
      }
}

// ---------- elementwise recurrence scan (16384 independent chains) ----------
#define SCAN_STEP(vv, adb, t)                                                \
  {                                                                          \
    uint bits = (adb);                                                       \
    __half ha_, hd_;                                                         \
    *reinterpret_cast<ushort*>(&ha_) = (ushort)(bits & 0xFFFF);              \
    *reinterpret_cast<ushort*>(&hd_) = (ushort)(bits >> 16);                 \
    float a = __half2float(ha_);                                             \
    float d = __half2float(hd_);                                             \
    float v = fmaf(r, h, (vv));                                              \
    float av = fminf(fmaxf(fabsf(v), 1e-6f), 10.0f);                         \
    float cand = copysignf(__builtin_amdgcn_exp2f(a * __builtin_amdgcn_logf(av)), v); \
    h = fmaf(d, cand - h, h);                                                \
    hout[(size_t)((t)+1)*BD + tid] = h;                                      \
    Hh[(size_t)(t)*BD + tid] = f2h(h);                                       \
  }

__global__ __launch_bounds__(64) void scan_kernel(
    const float* __restrict__ pv, const uint* __restrict__ pad,
    const float* __restrict__ rh, const float* __restrict__ h0,
    float* __restrict__ hout, ushort* __restrict__ Hh)
{
  int tid = blockIdx.x*64 + threadIdx.x;   // 0..16383 == b*DIM+e
  float r = rh[tid & (DIM-1)];
  float h = h0[tid];
  hout[tid] = h;                            // h[0] = h0

  float bufVA[G], bufVB[G];
  uint  bufDA[G], bufDB[G];

  #pragma unroll
  for (int i = 0; i < G; ++i) {
    bufVA[i] = pv [(size_t)i*BD + tid];
    bufDA[i] = pad[(size_t)i*BD + tid];
  }
  __builtin_amdgcn_sched_barrier(0);

  for (int gp = 0; gp < NG; gp += 2) {
    #pragma unroll
    for (int i = 0; i < G; ++i) {
      bufVB[i] = pv [(size_t)((gp+1)*G + i)*BD + tid];
      bufDB[i] = pad[(size_t)((gp+1)*G + i)*BD + tid];
    }
    __builtin_amdgcn_sched_barrier(0);
    #pragma unroll
    for (int i = 0; i < G; ++i) { SCAN_STEP(bufVA[i], bufDA[i], gp*G + i); }
    __builtin_amdgcn_sched_barrier(0);
    if (gp + 2 < NG) {
      #pragma unroll
      for (int i = 0; i < G; ++i) {
        bufVA[i] = pv [(size_t)((gp+2)*G + i)*BD + tid];
        bufDA[i] = pad[(size_t)((gp+2)*G + i)*BD + tid];
      }
    }
    __builtin_amdgcn_sched_barrier(0);
    #pragma unroll
    for (int i = 0; i < G; ++i) { SCAN_STEP(bufVB[i], bufDB[i], (gp+1)*G + i); }
    __builtin_amdgcn_sched_barrier(0);
  }
}

// ---------- compete softmax over contiguous groups of 32 ----------
__global__ __launch_bounds__(256) void compete_kernel(
    const float* __restrict__ h, float* __restrict__ comp)
{
  int g = blockIdx.x*256 + threadIdx.x;     // 524288 groups
  const float4* p = (const float4*)(h + (size_t)g*GSIZE);
  float vals[32];
  #pragma unroll
  for (int j = 0; j < 8; ++j) {
    float4 t4 = p[j];
    vals[4*j+0]=t4.x; vals[4*j+1]=t4.y; vals[4*j+2]=t4.z; vals[4*j+3]=t4.w;
  }
  float m = vals[0];
  #pragma unroll
  for (int j = 1; j < 32; ++j) m = fmaxf(m, vals[j]);
  float s = 0.f;
  #pragma unroll
  for (int j = 0; j < 32; ++j) { vals[j] = expf(vals[j]-m); s += vals[j]; }
  float inv = 1.f/s;
  float4* o = (float4*)(comp + (size_t)g*GSIZE);
  #pragma unroll
  for (int j = 0; j < 8; ++j) {
    float4 t4; t4.x=vals[4*j]*inv; t4.y=vals[4*j+1]*inv; t4.z=vals[4*j+2]*inv; t4.w=vals[4*j+3]*inv;
    o[j] = t4;
  }
}

extern "C" void kernel_launch(void* const* d_in, const int* in_sizes, int n_in,
                              void* d_out, int out_size, void* d_ws, size_t ws_size,
                              hipStream_t stream) {
  const float* x       = (const float*)d_in[0];
  const float* h0      = (const float*)d_in[1];
  const float* W_x     = (const float*)d_in[2];
  const float* r_h     = (const float*)d_in[3];
  const float* b       = (const float*)d_in[4];
  const float* W_alpha = (const float*)d_in[5];
  const float* b_alpha = (const float*)d_in[6];
  const float* W_delta = (const float*)d_in[7];
  const float* b_delta = (const float*)d_in[8];
  const float* W_out   = (const float*)d_in[9];

  float* out   = (float*)d_out;
  float* h_out = out;                                   // (T+1)*B*D
  float* outs  = out + (size_t)(TT+1)*BD;               // T*B*D

  char* p = (char*)d_ws;
  ushort* Xf  = (ushort*)p; p += (size_t)MROWS*DIM*2;   // 32MB f16
  ushort* Wxf = (ushort*)p; p += (size_t)DIM*DIM*2;
  ushort* Waf = (ushort*)p; p += (size_t)DIM*DIM*2;
  ushort* Wdf = (ushort*)p; p += (size_t)DIM*DIM*2;
  ushort* Wof = (ushort*)p; p += (size_t)DIM*DIM*2;
  float*  vxa = (float*)p;  p += (size_t)MROWS*DIM*4;   // 64MB
  uint*   ada = (uint*)p;   p += (size_t)MROWS*DIM*4;   // 64MB
  ushort* Hh  = (ushort*)p; p += (size_t)MROWS*DIM*2;   // 32MB f16
  float*  comp = (float*)p; p += (size_t)MROWS*DIM*4;   // 64MB

  split_x_kernel<<<2048, 256, 0, stream>>>((const float4*)x, (ushort4*)Xf, MROWS*DIM/4);
  split_w_kernel<<<1024, 256, 0, stream>>>((const float4*)W_x, (const float4*)W_alpha,
                                           (const float4*)W_delta, (const float4*)W_out,
                                           (ushort4*)Wxf, (ushort4*)Waf,
                                           (ushort4*)Wdf, (ushort4*)Wof, DIM*DIM/4);

  dim3 g(DIM/128, MROWS/128);
  gemm_vx_kernel<<<g, 256, 0, stream>>>(Xf, Wxf, b, vxa);
  gemm_ad_kernel<<<g, 512, 0, stream>>>(Xf, Waf, Wdf, b_alpha, b_delta, ada);

  scan_kernel<<<256, 64, 0, stream>>>(vxa, ada, r_h, h0, h_out, Hh);

  compete_kernel<<<2048, 256, 0, stream>>>(h_out + (size_t)BD, comp);

  gemm_out_kernel<<<g, 256, 0, stream>>>(Hh, Wof, comp, outs);
}